// Round 3
// baseline (191.422 us; speedup 1.0000x reference)
//
#include <hip/hip_runtime.h>
#include <hip/hip_bf16.h>

// Problem constants (B,T,C,HS) = (8,4096,1024,64)
#define BB 8
#define TT 4096
#define CC 1024
#define HS 64

typedef __attribute__((ext_vector_type(8))) __bf16 bf16x8;
typedef __attribute__((ext_vector_type(4))) __bf16 bf16x4;
typedef __attribute__((ext_vector_type(4))) float f32x4;

static __device__ __forceinline__ unsigned pack_bf16(float a, float b) {
    unsigned short ua = __builtin_bit_cast(unsigned short, (__bf16)a);
    unsigned short ub = __builtin_bit_cast(unsigned short, (__bf16)b);
    return (unsigned)ua | ((unsigned)ub << 16);
}

// ---------------------------------------------------------------------------
// Kernel 0: W prep.  Wt[192][1024] bf16 = [Wq^T * 0.125*log2(e) | Wk^T | Wv^T]
// (scale * log2e folded into Wq so softmax works in exp2 space)
// ---------------------------------------------------------------------------
__global__ __launch_bounds__(256) void wprep_kernel(
    const float* __restrict__ Wq, const float* __restrict__ Wk,
    const float* __restrict__ Wv, __bf16* __restrict__ Wt)
{
    int i = blockIdx.x * 256 + threadIdx.x;
    int dr = i >> 10;
    int c  = i & 1023;
    int m  = dr >> 6;
    int d  = dr & 63;
    const float* src = (m == 0) ? Wq : ((m == 1) ? Wk : Wv);
    float v = src[(long)c * HS + d];
    if (m == 0) v *= 0.125f * 1.4426950408889634f;
    Wt[i] = (__bf16)v;
}

// ---------------------------------------------------------------------------
// Kernel 1: QKV projection + RoPE.  One block = 64 token rows, 4 waves x 16.
// Q,K stored row-major [t][d]; V stored TRANSPOSED Vt[b*64+d][t] (via LDS).
// ---------------------------------------------------------------------------
__global__ __launch_bounds__(256) void qkv_rope_kernel(
    const float* __restrict__ x,     // [B*T][C]
    const float* __restrict__ cosT,  // [T][32]
    const float* __restrict__ sinT,  // [T][32]
    const __bf16* __restrict__ Wt,   // [192][1024]
    __bf16* __restrict__ Qo, __bf16* __restrict__ Ko, __bf16* __restrict__ Vo)
{
    __shared__ __bf16 xs[64][72];
    __shared__ __bf16 Wl[192][72];

    const int tid  = threadIdx.x;
    const int lane = tid & 63;
    const int w    = tid >> 6;
    const int col  = lane & 15;
    const int grp  = lane >> 4;
    const long rowbase = (long)blockIdx.x * 64;

    f32x4 acc[12];
#pragma unroll
    for (int i = 0; i < 12; i++) acc[i] = 0.0f;

    for (int ck = 0; ck < CC; ck += 64) {
        {
            int r = tid >> 2, c0 = (tid & 3) * 16;
            const float4* src = (const float4*)(x + (rowbase + r) * (long)CC + ck + c0);
#pragma unroll
            for (int i = 0; i < 4; i++) {
                float4 v = src[i];
                bf16x4 t;
                t[0] = (__bf16)v.x; t[1] = (__bf16)v.y;
                t[2] = (__bf16)v.z; t[3] = (__bf16)v.w;
                *(bf16x4*)&xs[r][c0 + i * 4] = t;
            }
        }
        {
#pragma unroll
            for (int i = 0; i < 6; i++) {
                int u = i * 256 + tid;
                int dr = u >> 3, cu = (u & 7) * 8;
                bf16x8 v = *(const bf16x8*)(Wt + (long)dr * CC + ck + cu);
                *(bf16x8*)&Wl[dr][cu] = v;
            }
        }
        __syncthreads();
#pragma unroll
        for (int s = 0; s < 2; s++) {
            bf16x8 a = *(const bf16x8*)&xs[w * 16 + col][s * 32 + grp * 8];
#pragma unroll
            for (int nf = 0; nf < 12; nf++) {
                bf16x8 b = *(const bf16x8*)&Wl[nf * 16 + col][s * 32 + grp * 8];
                acc[nf] = __builtin_amdgcn_mfma_f32_16x16x32_bf16(a, b, acc[nf], 0, 0, 0);
            }
        }
        __syncthreads();
    }

#pragma unroll
    for (int r = 0; r < 4; r++) {
        long grow = rowbase + w * 16 + grp * 4 + r;
        int t = (int)(grow & (TT - 1));
        const float* cp = cosT + (long)t * 32;
        const float* sp = sinT + (long)t * 32;
#pragma unroll
        for (int nf = 0; nf < 4; nf++) {
            int ii = nf * 8 + (col >> 1);
            float cs = cp[ii], sn = sp[ii];
            float sgn_sn = (col & 1) ? sn : -sn;
            float qv = acc[nf][r];
            float qp = __shfl_xor(qv, 1);
            float qo = qv * cs + qp * sgn_sn;
            float kv = acc[nf + 4][r];
            float kp = __shfl_xor(kv, 1);
            float ko = kv * cs + kp * sgn_sn;
            long base = grow * HS + nf * 16 + col;
            Qo[base] = (__bf16)qo;
            Ko[base] = (__bf16)ko;
            xs[nf * 16 + col][w * 16 + grp * 4 + r] = (__bf16)acc[nf + 8][r];
        }
    }
    __syncthreads();
    {
        int d = tid >> 2, seg = tid & 3;
        int b  = (int)(rowbase >> 12);
        int t0 = (int)(rowbase & (TT - 1));
        bf16x8 v0 = *(const bf16x8*)&xs[d][seg * 16];
        bf16x8 v1 = *(const bf16x8*)&xs[d][seg * 16 + 8];
        __bf16* dst = Vo + ((size_t)b * 64 + d) * TT + t0 + seg * 16;
        *(bf16x8*)dst = v0;
        *(bf16x8*)(dst + 8) = v1;
    }
}

// ---------------------------------------------------------------------------
// Kernel 2: barrier-free split-K causal flash attention.
// Each block = (batch, q-tile, kv-chunk of <=2^logch tiles), 4 waves x 16 q-rows.
// nch==1 -> normalized direct write to O; else unnormalized partial + (m,l).
// ---------------------------------------------------------------------------
__global__ __launch_bounds__(256) void attn_kernel(
    const __bf16* __restrict__ Q, const __bf16* __restrict__ K,
    const __bf16* __restrict__ Vt, float* __restrict__ O,
    float* __restrict__ Opart, float* __restrict__ ml,
    int logch, int maxnch)
{
    __shared__ __align__(16) unsigned char plds[4][2048];
    __shared__ float elds[4][16 * 72];

    const int tid  = threadIdx.x;
    const int lane = tid & 63;
    const int col  = lane & 15;
    const int g    = lane >> 4;
    const int w    = tid >> 6;

    const int n = blockIdx.x;
    const int b = n & 7;                 // batch pinned to XCD n%8
    int id = n >> 3;
    int qt = 0;
    for (;;) {
        int c = (qt >> logch) + 1;
        if (id < c) break;
        id -= c; qt++;
    }
    const int ch  = id;
    const int nch = (qt >> logch) + 1;
    const int j0  = ch << logch;
    const int j1  = min(qt + 1, j0 + (1 << logch));

    const size_t qrow = (size_t)b * TT + qt * 64 + w * 16 + col;
    bf16x8 qb[2];
#pragma unroll
    for (int s = 0; s < 2; s++)
        qb[s] = *(const bf16x8*)(Q + qrow * HS + s * 32 + g * 8);

    const __bf16* Kp = K + ((size_t)b * TT + col) * HS + g * 8;
    const __bf16* Vp = Vt + ((size_t)b * 64 + col) * TT + g * 8;

    f32x4 acc[4];
#pragma unroll
    for (int i = 0; i < 4; i++) acc[i] = 0.f;
    float mrun = -3e38f, lrun = 0.f;

    bf16x8 KA[8], KB[8], VF[8];
    unsigned char* pbase = plds[w] + col * 128;
    const int sw = col & 7;

    auto issueK = [&](int j, bf16x8 (&Kf)[8]) {
        const __bf16* p = Kp + (size_t)j * (64 * HS);
#pragma unroll
        for (int nf = 0; nf < 4; nf++)
#pragma unroll
            for (int s = 0; s < 2; s++)
                Kf[nf * 2 + s] = *(const bf16x8*)(p + nf * 16 * HS + s * 32);
    };
    auto issueV = [&](int j) {
        const __bf16* p = Vp + j * 64;
#pragma unroll
        for (int nf = 0; nf < 4; nf++)
#pragma unroll
            for (int s = 0; s < 2; s++)
                VF[nf * 2 + s] = *(const bf16x8*)(p + (size_t)nf * 16 * TT + s * 32);
    };

    auto tile = [&](const bf16x8 (&Kf)[8], bool diag) {
        f32x4 sf[4];
#pragma unroll
        for (int i = 0; i < 4; i++) sf[i] = 0.f;
#pragma unroll
        for (int s = 0; s < 2; s++)
#pragma unroll
            for (int nf = 0; nf < 4; nf++)
                sf[nf] = __builtin_amdgcn_mfma_f32_16x16x32_bf16(Kf[nf * 2 + s], qb[s], sf[nf], 0, 0, 0);
        if (diag) {
#pragma unroll
            for (int nf = 0; nf < 4; nf++)
#pragma unroll
                for (int r = 0; r < 4; r++)
                    if (nf * 16 + g * 4 + r > w * 16 + col) sf[nf][r] = -3e38f;
        }
        float mt = sf[0][0];
#pragma unroll
        for (int nf = 0; nf < 4; nf++)
#pragma unroll
            for (int r = 0; r < 4; r++) mt = fmaxf(mt, sf[nf][r]);
        mt = fmaxf(mt, __shfl_xor(mt, 16));
        mt = fmaxf(mt, __shfl_xor(mt, 32));
        float mn = fmaxf(mrun, mt);
        float al = exp2f(mrun - mn);
        mrun = mn;
        float sum = 0.f;
#pragma unroll
        for (int nf = 0; nf < 4; nf++)
#pragma unroll
            for (int r = 0; r < 4; r++) {
                float pp = exp2f(sf[nf][r] - mn);
                sf[nf][r] = pp;
                sum += pp;
            }
        sum += __shfl_xor(sum, 16);
        sum += __shfl_xor(sum, 32);
        lrun = lrun * al + sum;
#pragma unroll
        for (int nf = 0; nf < 4; nf++) acc[nf] *= al;
#pragma unroll
        for (int nf = 0; nf < 4; nf++) {
            uint2 val;
            val.x = pack_bf16(sf[nf][0], sf[nf][1]);
            val.y = pack_bf16(sf[nf][2], sf[nf][3]);
            *(uint2*)(pbase + ((((nf * 2 + (g >> 1)) ^ sw) << 4) | ((g & 1) << 3))) = val;
        }
#pragma unroll
        for (int s = 0; s < 2; s++) {
            bf16x8 pf = *(const bf16x8*)(pbase + (((s * 4 + g) ^ sw) << 4));
#pragma unroll
            for (int nf = 0; nf < 4; nf++)
                acc[nf] = __builtin_amdgcn_mfma_f32_16x16x32_bf16(VF[nf * 2 + s], pf, acc[nf], 0, 0, 0);
        }
    };

    issueK(j0, KA);
    int j = j0;
    for (;;) {
        issueV(j);
        if (j + 1 < j1) issueK(j + 1, KB);
        tile(KA, j == qt);
        if (j + 1 >= j1) break;
        issueV(j + 1);
        if (j + 2 < j1) issueK(j + 2, KA);
        tile(KB, j + 1 == qt);
        j += 2;
        if (j >= j1) break;
    }

    // epilogue: transpose via wave-private LDS, coalesced store
    float rinv = (nch == 1) ? __builtin_amdgcn_rcpf(lrun) : 1.0f;
#pragma unroll
    for (int nf = 0; nf < 4; nf++)
#pragma unroll
        for (int r = 0; r < 4; r++)
            elds[w][col * 72 + nf * 16 + g * 4 + r] = acc[nf][r] * rinv;

    if (nch == 1) {
        int ql = lane >> 2, seg = lane & 3;
        size_t orow = (size_t)b * TT + qt * 64 + w * 16 + ql;
#pragma unroll
        for (int p = 0; p < 4; p++) {
            float4 v = *(const float4*)&elds[w][ql * 72 + p * 16 + seg * 4];
            *(float4*)(O + orow * HS + p * 16 + seg * 4) = v;
        }
    } else {
        size_t base = ((size_t)b * 64 + qt) * maxnch + ch;
        int ql = lane >> 2, seg = lane & 3;
        float* dst = Opart + (base * 64 + w * 16 + ql) * 64;
#pragma unroll
        for (int p = 0; p < 4; p++) {
            float4 v = *(const float4*)&elds[w][ql * 72 + p * 16 + seg * 4];
            *(float4*)(dst + p * 16 + seg * 4) = v;
        }
        if (g == 0) {
            float2 mv = make_float2(mrun, lrun);
            *(float2*)(ml + (base * 64 + w * 16 + col) * 2) = mv;
        }
    }
}

// ---------------------------------------------------------------------------
// Kernel 3: combine split-K partials.
// ---------------------------------------------------------------------------
__global__ __launch_bounds__(256) void combine_kernel(
    const float* __restrict__ Opart, const float* __restrict__ ml,
    float* __restrict__ O, int logch, int maxnch)
{
    const int qt = blockIdx.x;
    const int b  = blockIdx.y;
    const int nch = (qt >> logch) + 1;
    if (nch < 2) return;
    const int row = threadIdx.x >> 2;
    const int seg = threadIdx.x & 3;
    const size_t base = ((size_t)b * 64 + qt) * maxnch;

    float mv[4], lv[4], wgt[4];
    float M = -3e38f;
    for (int c = 0; c < nch; c++) {
        const float* p = ml + (base + c) * 128 + row * 2;
        mv[c] = p[0]; lv[c] = p[1];
        M = fmaxf(M, mv[c]);
    }
    float L = 0.f;
    for (int c = 0; c < nch; c++) { wgt[c] = exp2f(mv[c] - M); L += lv[c] * wgt[c]; }
    float rinv = 1.0f / L;
    for (int c = 0; c < nch; c++) wgt[c] *= rinv;

    float4 acc[4];
#pragma unroll
    for (int i = 0; i < 4; i++) acc[i] = make_float4(0.f, 0.f, 0.f, 0.f);
    for (int c = 0; c < nch; c++) {
        const float4* src = (const float4*)(Opart + ((base + c) * 64 + row) * 64 + seg * 16);
        float wc = wgt[c];
#pragma unroll
        for (int i = 0; i < 4; i++) {
            float4 v = src[i];
            acc[i].x += v.x * wc; acc[i].y += v.y * wc;
            acc[i].z += v.z * wc; acc[i].w += v.w * wc;
        }
    }
    float4* dst = (float4*)(O + ((size_t)b * TT + qt * 64 + row) * 64 + seg * 16);
#pragma unroll
    for (int i = 0; i < 4; i++) dst[i] = acc[i];
}

// ---------------------------------------------------------------------------
extern "C" void kernel_launch(void* const* d_in, const int* in_sizes, int n_in,
                              void* d_out, int out_size, void* d_ws, size_t ws_size,
                              hipStream_t stream)
{
    const float* x    = (const float*)d_in[0];
    const float* cosT = (const float*)d_in[1];
    const float* sinT = (const float*)d_in[2];
    const float* Wq   = (const float*)d_in[3];
    const float* Wk   = (const float*)d_in[4];
    const float* Wv   = (const float*)d_in[5];
    float* out = (float*)d_out;

    __bf16* Qb = (__bf16*)d_ws;
    __bf16* Kb = Qb + (size_t)BB * TT * HS;
    __bf16* Vb = Kb + (size_t)BB * TT * HS;   // transposed: [b*64+d][t]
    __bf16* Wt = Vb + (size_t)BB * TT * HS;

    const size_t base_bytes = (size_t)3 * BB * TT * HS * 2 + 192 * 1024 * 2;
    // per-maxnch extra: 8 b * 64 qt * (64*64 Opart + 64*2 ml) floats
    const size_t unit = (size_t)8 * 64 * (4096 + 128) * 4;   // 8,650,752 B
    int logch;
    if      (ws_size >= base_bytes + 4 * unit) logch = 4;
    else if (ws_size >= base_bytes + 2 * unit) logch = 5;
    else                                       logch = 6;   // no split
    const int maxnch = 64 >> logch;

    float* mlbuf = (float*)((char*)d_ws + base_bytes);
    float* Opart = mlbuf + (size_t)maxnch * 8 * 64 * 64 * 2;

    int nb = 0;
    for (int qt = 0; qt < 64; qt++) nb += (qt >> logch) + 1;
    nb *= 8;

    wprep_kernel<<<(192 * 1024) / 256, 256, 0, stream>>>(Wq, Wk, Wv, Wt);
    qkv_rope_kernel<<<(BB * TT) / 64, 256, 0, stream>>>(x, cosT, sinT, Wt, Qb, Kb, Vb);
    attn_kernel<<<nb, 256, 0, stream>>>(Qb, Kb, Vb, out, Opart, mlbuf, logch, maxnch);
    if (maxnch > 1)
        combine_kernel<<<dim3(64, 8), 256, 0, stream>>>(Opart, mlbuf, out, logch, maxnch);
}

// Round 4
// 160.810 us; speedup vs baseline: 1.1904x; 1.1904x over previous
//
#include <hip/hip_runtime.h>
#include <hip/hip_bf16.h>

// Problem constants (B,T,C,HS) = (8,4096,1024,64)
#define BB 8
#define TT 4096
#define CC 1024
#define HS 64

typedef __attribute__((ext_vector_type(8))) __bf16 bf16x8;
typedef __attribute__((ext_vector_type(4))) __bf16 bf16x4;
typedef __attribute__((ext_vector_type(4))) float f32x4;

static __device__ __forceinline__ unsigned pack_bf16(float a, float b) {
    unsigned short ua = __builtin_bit_cast(unsigned short, (__bf16)a);
    unsigned short ub = __builtin_bit_cast(unsigned short, (__bf16)b);
    return (unsigned)ua | ((unsigned)ub << 16);
}

// ---------------------------------------------------------------------------
// Kernel 0: W prep.  Wt[192][1024] bf16 = [Wq^T * 0.125*log2(e) | Wk^T | Wv^T]
// ---------------------------------------------------------------------------
__global__ __launch_bounds__(256) void wprep_kernel(
    const float* __restrict__ Wq, const float* __restrict__ Wk,
    const float* __restrict__ Wv, __bf16* __restrict__ Wt)
{
    int i = blockIdx.x * 256 + threadIdx.x;
    int dr = i >> 10;
    int c  = i & 1023;
    int m  = dr >> 6;
    int d  = dr & 63;
    const float* src = (m == 0) ? Wq : ((m == 1) ? Wk : Wv);
    float v = src[(long)c * HS + d];
    if (m == 0) v *= 0.125f * 1.4426950408889634f;   // scale * log2e into Wq
    Wt[i] = (__bf16)v;
}

// ---------------------------------------------------------------------------
// Kernel 1: QKV projection + RoPE.  One block = 64 token rows, 4 waves x 16.
// Q,K stored row-major [t][d]; V stored TRANSPOSED Vt[b*64+d][t] (via LDS).
// ---------------------------------------------------------------------------
__global__ __launch_bounds__(256) void qkv_rope_kernel(
    const float* __restrict__ x,     // [B*T][C]
    const float* __restrict__ cosT,  // [T][32]
    const float* __restrict__ sinT,  // [T][32]
    const __bf16* __restrict__ Wt,   // [192][1024]
    __bf16* __restrict__ Qo, __bf16* __restrict__ Ko, __bf16* __restrict__ Vo)
{
    __shared__ __bf16 xs[64][72];
    __shared__ __bf16 Wl[192][72];

    const int tid  = threadIdx.x;
    const int lane = tid & 63;
    const int w    = tid >> 6;
    const int col  = lane & 15;
    const int grp  = lane >> 4;
    const long rowbase = (long)blockIdx.x * 64;

    f32x4 acc[12];
#pragma unroll
    for (int i = 0; i < 12; i++) acc[i] = 0.0f;

    for (int ck = 0; ck < CC; ck += 64) {
        {
            int r = tid >> 2, c0 = (tid & 3) * 16;
            const float4* src = (const float4*)(x + (rowbase + r) * (long)CC + ck + c0);
#pragma unroll
            for (int i = 0; i < 4; i++) {
                float4 v = src[i];
                bf16x4 t;
                t[0] = (__bf16)v.x; t[1] = (__bf16)v.y;
                t[2] = (__bf16)v.z; t[3] = (__bf16)v.w;
                *(bf16x4*)&xs[r][c0 + i * 4] = t;
            }
        }
        {
#pragma unroll
            for (int i = 0; i < 6; i++) {
                int u = i * 256 + tid;
                int dr = u >> 3, cu = (u & 7) * 8;
                bf16x8 v = *(const bf16x8*)(Wt + (long)dr * CC + ck + cu);
                *(bf16x8*)&Wl[dr][cu] = v;
            }
        }
        __syncthreads();
#pragma unroll
        for (int s = 0; s < 2; s++) {
            bf16x8 a = *(const bf16x8*)&xs[w * 16 + col][s * 32 + grp * 8];
#pragma unroll
            for (int nf = 0; nf < 12; nf++) {
                bf16x8 b = *(const bf16x8*)&Wl[nf * 16 + col][s * 32 + grp * 8];
                acc[nf] = __builtin_amdgcn_mfma_f32_16x16x32_bf16(a, b, acc[nf], 0, 0, 0);
            }
        }
        __syncthreads();
    }

#pragma unroll
    for (int r = 0; r < 4; r++) {
        long grow = rowbase + w * 16 + grp * 4 + r;
        int t = (int)(grow & (TT - 1));
        const float* cp = cosT + (long)t * 32;
        const float* sp = sinT + (long)t * 32;
#pragma unroll
        for (int nf = 0; nf < 4; nf++) {
            int ii = nf * 8 + (col >> 1);
            float cs = cp[ii], sn = sp[ii];
            float sgn_sn = (col & 1) ? sn : -sn;
            float qv = acc[nf][r];
            float qp = __shfl_xor(qv, 1);
            float qo = qv * cs + qp * sgn_sn;
            float kv = acc[nf + 4][r];
            float kp = __shfl_xor(kv, 1);
            float ko = kv * cs + kp * sgn_sn;
            long base = grow * HS + nf * 16 + col;
            Qo[base] = (__bf16)qo;
            Ko[base] = (__bf16)ko;
            xs[nf * 16 + col][w * 16 + grp * 4 + r] = (__bf16)acc[nf + 8][r];
        }
    }
    __syncthreads();
    {
        int d = tid >> 2, seg = tid & 3;
        int b  = (int)(rowbase >> 12);
        int t0 = (int)(rowbase & (TT - 1));
        bf16x8 v0 = *(const bf16x8*)&xs[d][seg * 16];
        bf16x8 v1 = *(const bf16x8*)&xs[d][seg * 16 + 8];
        __bf16* dst = Vo + ((size_t)b * 64 + d) * TT + t0 + seg * 16;
        *(bf16x8*)dst = v0;
        *(bf16x8*)(dst + 8) = v1;
    }
}

// ---------------------------------------------------------------------------
// Kernel 2: barrier-free causal flash attention, pair-fused KV tiles (128 kv
// per softmax), defer-max (THR=8 in exp2 space), deferred l-sum combine.
// Grid 512: n<256 -> qt=63-k (heavy first), n>=256 -> qt=k; blocks n and n+256
// land on the same CU under round-robin => per-CU work = 65 tiles.
// ---------------------------------------------------------------------------
__global__ __launch_bounds__(256) void attn_kernel(
    const __bf16* __restrict__ Q, const __bf16* __restrict__ K,
    const __bf16* __restrict__ Vt, float* __restrict__ O)
{
    __shared__ __align__(16) unsigned char plds[4][16 * 256];  // 16 q x 128 kv bf16 per wave
    __shared__ float elds[4][16 * 72];

    const int tid  = threadIdx.x;
    const int lane = tid & 63;
    const int col  = lane & 15;
    const int g    = lane >> 4;
    const int w    = tid >> 6;

    const int n = blockIdx.x;
    const int b = n & 7;
    const int k = (n >> 3) & 31;
    const int qt = (n < 256) ? (63 - k) : k;

    const int qglob = qt * 64 + w * 16 + col;          // this lane's q row (in seq)
    const size_t qrow = (size_t)b * TT + qglob;
    bf16x8 qb[2];
#pragma unroll
    for (int s = 0; s < 2; s++)
        qb[s] = *(const bf16x8*)(Q + qrow * HS + s * 32 + g * 8);

    const __bf16* Kp = K + ((size_t)b * TT + col) * HS + g * 8;
    const __bf16* Vp = Vt + ((size_t)b * 64 + col) * TT + g * 8;

    f32x4 acc[4];
#pragma unroll
    for (int i = 0; i < 4; i++) acc[i] = 0.f;
    float mrun = -3e38f;
    float lsum0 = 0.f, lsum1 = 0.f, lsum2 = 0.f, lsum3 = 0.f;

    bf16x8 K0[8], K1[8], V0[8], V1[8];
    unsigned char* pbase = plds[w] + col * 256;
    const int sw = col;                                 // 16-chunk XOR swizzle

    auto issueK = [&](int j, bf16x8 (&Kf)[8]) {
        const __bf16* p = Kp + (size_t)j * (64 * HS);
#pragma unroll
        for (int nf = 0; nf < 4; nf++)
#pragma unroll
            for (int s = 0; s < 2; s++)
                Kf[nf * 2 + s] = *(const bf16x8*)(p + nf * 16 * HS + s * 32);
    };
    auto issueV = [&](int j, bf16x8 (&Vf)[8]) {
        const __bf16* p = Vp + j * 64;
#pragma unroll
        for (int nf = 0; nf < 4; nf++)
#pragma unroll
            for (int s = 0; s < 2; s++)
                Vf[nf * 2 + s] = *(const bf16x8*)(p + (size_t)nf * 16 * TT + s * 32);
    };

    issueK(0, K0);
    if (qt >= 1) issueK(1, K1);

    for (int p = 0; p <= qt; p += 2) {
        issueV(p, V0);
        if (p + 1 <= qt) issueV(p + 1, V1);

        // ---- S^T for both tiles ----
        f32x4 sf[8];
#pragma unroll
        for (int i = 0; i < 8; i++) sf[i] = 0.f;
#pragma unroll
        for (int s = 0; s < 2; s++)
#pragma unroll
            for (int nf = 0; nf < 4; nf++)
                sf[nf] = __builtin_amdgcn_mfma_f32_16x16x32_bf16(K0[nf * 2 + s], qb[s], sf[nf], 0, 0, 0);
        if (p + 2 <= qt) issueK(p + 2, K0);
#pragma unroll
        for (int s = 0; s < 2; s++)
#pragma unroll
            for (int nf = 0; nf < 4; nf++)
                sf[4 + nf] = __builtin_amdgcn_mfma_f32_16x16x32_bf16(K1[nf * 2 + s], qb[s], sf[4 + nf], 0, 0, 0);
        if (p + 3 <= qt) issueK(p + 3, K1);

        // ---- causal / tail masking (only the last pair needs it) ----
        if (p + 2 > qt) {
#pragma unroll
            for (int h = 0; h < 2; h++) {
                int kvb = (p + h) * 64;
                bool bad = (p + h > qt);
#pragma unroll
                for (int nf = 0; nf < 4; nf++)
#pragma unroll
                    for (int r = 0; r < 4; r++)
                        if (bad || kvb + nf * 16 + g * 4 + r > qglob)
                            sf[h * 4 + nf][r] = -3e38f;
            }
        }

        // ---- per-lane tree max over 32 values ----
        float fm[8];
#pragma unroll
        for (int f = 0; f < 8; f++)
            fm[f] = fmaxf(fmaxf(sf[f][0], sf[f][1]), fmaxf(sf[f][2], sf[f][3]));
        float m01 = fmaxf(fm[0], fm[1]), m23 = fmaxf(fm[2], fm[3]);
        float m45 = fmaxf(fm[4], fm[5]), m67 = fmaxf(fm[6], fm[7]);
        float mt  = fmaxf(fmaxf(m01, m23), fmaxf(m45, m67));

        // ---- defer-max: only update running max when growth > 8 (exp2 units)
        if (!__all(mt <= mrun + 8.0f)) {
            float mg = fmaxf(mt, __shfl_xor(mt, 16));
            mg = fmaxf(mg, __shfl_xor(mg, 32));
            float mn = fmaxf(mrun, mg);
            float al = exp2f(mrun - mn);
            mrun = mn;
            lsum0 *= al; lsum1 *= al; lsum2 *= al; lsum3 *= al;
#pragma unroll
            for (int nf = 0; nf < 4; nf++) acc[nf] *= al;
        }

        // ---- exp + per-lane partial sums (4 independent chains) ----
#pragma unroll
        for (int f = 0; f < 8; f++) {
            float p0 = exp2f(sf[f][0] - mrun);
            float p1 = exp2f(sf[f][1] - mrun);
            float p2 = exp2f(sf[f][2] - mrun);
            float p3 = exp2f(sf[f][3] - mrun);
            sf[f][0] = p0; sf[f][1] = p1; sf[f][2] = p2; sf[f][3] = p3;
            lsum0 += p0; lsum1 += p1; lsum2 += p2; lsum3 += p3;
        }

        // ---- P^T -> P rows via wave-private swizzled LDS bounce ----
#pragma unroll
        for (int f = 0; f < 8; f++) {
            int t = f >> 2, nf = f & 3;
            int c_raw = t * 8 + nf * 2 + (g >> 1);
            uint2 val;
            val.x = pack_bf16(sf[f][0], sf[f][1]);
            val.y = pack_bf16(sf[f][2], sf[f][3]);
            *(uint2*)(pbase + ((((c_raw ^ sw) << 4)) | ((g & 1) << 3))) = val;
        }
        // ---- O^T += V P for both tiles ----
#pragma unroll
        for (int t = 0; t < 2; t++)
#pragma unroll
            for (int s = 0; s < 2; s++) {
                int c_raw = t * 8 + s * 4 + g;
                bf16x8 pf = *(const bf16x8*)(pbase + ((c_raw ^ sw) << 4));
                const bf16x8* Vf = (t == 0) ? V0 : V1;
#pragma unroll
                for (int nf = 0; nf < 4; nf++)
                    acc[nf] = __builtin_amdgcn_mfma_f32_16x16x32_bf16(Vf[nf * 2 + s], pf, acc[nf], 0, 0, 0);
            }
    }

    // ---- final l combine: 4 chains + cross-lane-group ----
    float ls = (lsum0 + lsum1) + (lsum2 + lsum3);
    ls += __shfl_xor(ls, 16);
    ls += __shfl_xor(ls, 32);
    float rinv = __builtin_amdgcn_rcpf(ls);

    // ---- epilogue: transpose via wave-private LDS, coalesced store ----
#pragma unroll
    for (int nf = 0; nf < 4; nf++)
#pragma unroll
        for (int r = 0; r < 4; r++)
            elds[w][col * 72 + nf * 16 + g * 4 + r] = acc[nf][r] * rinv;
    {
        int ql = lane >> 2, seg = lane & 3;
        size_t orow = (size_t)b * TT + qt * 64 + w * 16 + ql;
#pragma unroll
        for (int pp = 0; pp < 4; pp++) {
            float4 v = *(const float4*)&elds[w][ql * 72 + pp * 16 + seg * 4];
            *(float4*)(O + orow * HS + pp * 16 + seg * 4) = v;
        }
    }
}

// ---------------------------------------------------------------------------
extern "C" void kernel_launch(void* const* d_in, const int* in_sizes, int n_in,
                              void* d_out, int out_size, void* d_ws, size_t ws_size,
                              hipStream_t stream)
{
    const float* x    = (const float*)d_in[0];
    const float* cosT = (const float*)d_in[1];
    const float* sinT = (const float*)d_in[2];
    const float* Wq   = (const float*)d_in[3];
    const float* Wk   = (const float*)d_in[4];
    const float* Wv   = (const float*)d_in[5];
    float* out = (float*)d_out;

    __bf16* Qb = (__bf16*)d_ws;
    __bf16* Kb = Qb + (size_t)BB * TT * HS;
    __bf16* Vb = Kb + (size_t)BB * TT * HS;   // transposed: [b*64+d][t]
    __bf16* Wt = Vb + (size_t)BB * TT * HS;   // also absorbs tail-tile overreads

    wprep_kernel<<<(192 * 1024) / 256, 256, 0, stream>>>(Wq, Wk, Wv, Wt);
    qkv_rope_kernel<<<(BB * TT) / 64, 256, 0, stream>>>(x, cosT, sinT, Wt, Qb, Kb, Vb);
    attn_kernel<<<512, 256, 0, stream>>>(Qb, Kb, Vb, out);
}